// Round 2
// baseline (338.341 us; speedup 1.0000x reference)
//
#include <hip/hip_runtime.h>
#include <hip/hip_cooperative_groups.h>

namespace cg = cooperative_groups;

// Head: single-head causal attention. B=4, T=2048, D=1024, H=64. fp32 in/out.
// R11: single cooperative kernel, 4 phases separated by grid.sync().
//  - Phase bodies are byte-identical to R10's four kernels (grid-stride
//    work distribution only) to isolate the fusion effect.
//  - __launch_bounds__(256,4): VGPR<=128 -> 4 blocks/CU -> grid 1024+
//    co-resident; host clamps grid via occupancy query.
//
// ws layout (bytes):
//   [0,        393216)   wtf   bf16 [12][128][16][8]   (fragment-ordered W)
//   [393216,  1441792)   qf    bf16 [512][8][16][8]    (fragment-ordered Q)
//   [1441792, 2490368)   kf    bf16 [512][8][16][8]
//   [2490368, 3538944)   vf    bf16 [4][32][4][8][16][8]
//   [3538944, 12451840)  Opart bf16 [4352][16][64]     (unit-indexed)
//   [12451840,12730368)  mpart fp32 [4352][16]
//   [12730368,13008896)  lpart fp32 [4352][16]

typedef __attribute__((ext_vector_type(8))) __bf16 bf16x8;
typedef __attribute__((ext_vector_type(4))) float floatx4;

union BF8 {
    bf16x8 v;
    unsigned short s[8];
    uint4 u;
};
union BF4 {
    unsigned short s[4];
    unsigned long long ull;
};

__device__ inline unsigned short f2bf(float f) {
    unsigned int u = __float_as_uint(f);
    unsigned int r = (u + 0x7fffu + ((u >> 16) & 1u)) >> 16;
    return (unsigned short)r;
}
__device__ inline float bf2f(unsigned short s) {
    unsigned int u = ((unsigned int)s) << 16;
    return __uint_as_float(u);
}

// ---------------------------------------------------------------------------
// Phase 0: W -> wtf fragment layout. 48 units.
// ---------------------------------------------------------------------------
__device__ __forceinline__ void wt_body(int u, int tid, unsigned short* lt,
                                        const float* __restrict__ Wq,
                                        const float* __restrict__ Wk,
                                        const float* __restrict__ Wv,
                                        unsigned short* __restrict__ wtf) {
    const int sel = u >> 4;
    const int kb = u & 15;
    const float* W = (sel == 0) ? Wq : (sel == 1) ? Wk : Wv;

    const int h = tid & 63;
    const int kr = tid >> 6;
#pragma unroll
    for (int i = 0; i < 16; ++i) {
        const int kkl = kr + i * 4;
        lt[kkl * 72 + h] = f2bf(W[(size_t)(kb * 64 + kkl) * 64 + h]);
    }
    __syncthreads();

#pragma unroll
    for (int s = 0; s < 2; ++s) {
        const int seg = tid + s * 256;
        const int l16 = seg & 15;
        const int rest = seg >> 4;
        const int ko = rest & 7;
        const int hb = rest >> 3;
        const int hh = hb * 16 + l16;
        BF8 o;
#pragma unroll
        for (int j = 0; j < 8; ++j) o.s[j] = lt[(ko * 8 + j) * 72 + hh];
        const int nblk = sel * 4 + hb;
        const int koct = kb * 8 + ko;
        *(uint4*)(wtf + ((size_t)nblk * 128 + koct) * 128 + l16 * 8) = o.u;
    }
    __syncthreads();
}

// ---------------------------------------------------------------------------
// Phase 1: QKV projection. 512 units (16-row m-tiles).
// ---------------------------------------------------------------------------
__device__ __forceinline__ void qkv_body(int u, int tid, unsigned char* smem,
                                         const float* __restrict__ x,
                                         const unsigned short* __restrict__ wtf,
                                         unsigned short* __restrict__ qf,
                                         unsigned short* __restrict__ kf,
                                         unsigned short* __restrict__ vf) {
    unsigned short* lxbase = (unsigned short*)smem;                 // [2][16*136]
    unsigned short* lt = (unsigned short*)(smem + 8704);            // [16*200]
    unsigned short* vtile = (unsigned short*)(smem + 8704 + 6400);  // [64*24]

    const int w = tid >> 6;  // col-group: 48 cols each
    const int lane = tid & 63;
    const int quad = lane >> 4;
    const int l16 = lane & 15;
    const int m0 = u * 16;
    const int b = m0 >> 11;

    const int srow = tid >> 4;  // 0..15
    const int sc = tid & 15;    // float4 slot (2 per thread: sc, sc+16)

    float4 ld[2];
    const float* xbase = x + (size_t)(m0 + srow) * 1024 + sc * 4;

#define LOAD_CHUNK(c)                               \
    {                                               \
        const float* p_ = xbase + (c) * 128;        \
        ld[0] = *(const float4*)(p_);               \
        ld[1] = *(const float4*)(p_ + 64);          \
    }
#define WRITE_CHUNK(buf)                                              \
    {                                                                 \
        unsigned short* p_ = lxbase + (buf)*2176 + srow * 136 + sc * 4; \
        BF4 b0_, b1_;                                                 \
        b0_.s[0] = f2bf(ld[0].x); b0_.s[1] = f2bf(ld[0].y);           \
        b0_.s[2] = f2bf(ld[0].z); b0_.s[3] = f2bf(ld[0].w);           \
        b1_.s[0] = f2bf(ld[1].x); b1_.s[1] = f2bf(ld[1].y);           \
        b1_.s[2] = f2bf(ld[1].z); b1_.s[3] = f2bf(ld[1].w);           \
        *(unsigned long long*)(p_) = b0_.ull;                         \
        *(unsigned long long*)(p_ + 64) = b1_.ull;                    \
    }

    floatx4 acc[3];
#pragma unroll
    for (int i = 0; i < 3; ++i) acc[i] = (floatx4)(0.0f);

    LOAD_CHUNK(0);
    WRITE_CHUNK(0);
    __syncthreads();

    for (int c = 0; c < 8; ++c) {
        if (c < 7) LOAD_CHUNK(c + 1);
        const unsigned short* lp = lxbase + (c & 1) * 2176 + l16 * 136 + quad * 8;
#pragma unroll
        for (int kst = 0; kst < 4; ++kst) {
            BF8 a;
            a.u = *(const uint4*)(lp + kst * 32);
            const int koct = c * 16 + kst * 4 + quad;
#pragma unroll
            for (int nt = 0; nt < 3; ++nt) {
                const int nb = w * 3 + nt;
                BF8 bfr;
                bfr.u = *(const uint4*)(wtf + ((size_t)nb * 128 + koct) * 128 + l16 * 8);
                acc[nt] = __builtin_amdgcn_mfma_f32_16x16x32_bf16(a.v, bfr.v, acc[nt], 0, 0, 0);
            }
        }
        if (c < 7) WRITE_CHUNK((c + 1) & 1);
        __syncthreads();
    }

    // epilogue: stash C-tiles. cols 0..127 (q,k) -> lt row-major; 128..191 (v)
    // -> vtile (4 consecutive t packed per lane).
#pragma unroll
    for (int nt = 0; nt < 3; ++nt) {
        const int ngl = w * 48 + nt * 16;
        if (ngl < 128) {
#pragma unroll
            for (int r = 0; r < 4; ++r)
                lt[(quad * 4 + r) * 200 + ngl + l16] = f2bf(acc[nt][r]);
        } else {
            BF4 pk;
#pragma unroll
            for (int r = 0; r < 4; ++r) pk.s[r] = f2bf(acc[nt][r]);
            *(unsigned long long*)&vtile[(ngl - 128 + l16) * 24 + quad * 4] = pk.ull;
        }
    }
    __syncthreads();

    // q/k emission: 256 segs of 16B; 16 consecutive tids -> 256B contiguous.
    {
        const int row = tid & 15;
        const int koct = tid >> 4;  // 0..15
        uint4 seg = *(const uint4*)&lt[row * 200 + koct * 8];
        const size_t tile = u;  // = b*128 + qt
        if (koct < 8)
            *(uint4*)(qf + tile * 1024 + koct * 128 + row * 8) = seg;
        else
            *(uint4*)(kf + tile * 1024 + (koct - 8) * 128 + row * 8) = seg;
    }
    // v emission: 128 segs of 16B (8 consecutive t at fixed h).
    if (tid < 128) {
        const int h = tid >> 1;
        const int sg = tid & 1;
        uint4 seg = *(const uint4*)&vtile[h * 24 + sg * 8];
        const int jt = (m0 & 2047) >> 6;
        const int koct = ((m0 & 63) >> 3) + sg;
        *(uint4*)(vf + (((size_t)(b * 32 + jt) * 4 + (h >> 4)) * 8 + koct) * 128 +
                  (h & 15) * 8) = seg;
    }
    __syncthreads();
#undef LOAD_CHUNK
#undef WRITE_CHUNK
}

// ---------------------------------------------------------------------------
// Phase 2: flash pass A. 4352 wave-units. Static two-tile flow + V register
// prefetch + LDS-packed Opart store (R10 code).
// ---------------------------------------------------------------------------
__device__ __forceinline__ void attn_tile(int j0, int r0, int b, int lane, int quad,
                                          int l16,
                                          const unsigned short* __restrict__ kf,
                                          const unsigned short* __restrict__ vf,
                                          unsigned short* myp, const BF8* aq,
                                          floatx4* oacc, float* m_i, float* l_i) {
    floatx4 s[4];
#pragma unroll
    for (int nt = 0; nt < 4; ++nt) s[nt] = (floatx4)(0.0f);
#pragma unroll
    for (int kst = 0; kst < 2; ++kst) {
#pragma unroll
        for (int nt = 0; nt < 4; ++nt) {
            BF8 bk;
            bk.u = *(const uint4*)(kf + (size_t)(b * 128 + (j0 >> 4) + nt) * 1024 +
                                   kst * 512 + lane * 8);
            s[nt] = __builtin_amdgcn_mfma_f32_16x16x32_bf16(aq[kst].v, bk.v, s[nt], 0, 0, 0);
        }
    }

    // V prefetch (kst=0): independent of softmax -> lands under softmax VALU.
    BF8 bv0[4];
#pragma unroll
    for (int nt = 0; nt < 4; ++nt)
        bv0[nt].u = *(const uint4*)(vf + ((size_t)(b * 32 + (j0 >> 6)) * 4 + nt) * 1024 +
                                    lane * 8);

    float sv[4][4];
    const bool masked = (j0 + 63 > r0);
#pragma unroll
    for (int nt = 0; nt < 4; ++nt)
#pragma unroll
        for (int r = 0; r < 4; ++r) {
            float val = s[nt][r] * 0.125f;
            if (masked) {
                int key = j0 + nt * 16 + l16;
                int qr = r0 + quad * 4 + r;
                if (key > qr) val = -3.0e38f;
            }
            sv[nt][r] = val;
        }

    float alpha[4];
#pragma unroll
    for (int r = 0; r < 4; ++r) {
        float mx = fmaxf(fmaxf(sv[0][r], sv[1][r]), fmaxf(sv[2][r], sv[3][r]));
        mx = fmaxf(mx, __shfl_xor(mx, 1));
        mx = fmaxf(mx, __shfl_xor(mx, 2));
        mx = fmaxf(mx, __shfl_xor(mx, 4));
        mx = fmaxf(mx, __shfl_xor(mx, 8));
        float mn = fmaxf(m_i[r], mx);
        alpha[r] = __expf(m_i[r] - mn);
        m_i[r] = mn;
    }
    float rs[4] = {0.f, 0.f, 0.f, 0.f};
#pragma unroll
    for (int nt = 0; nt < 4; ++nt)
#pragma unroll
        for (int r = 0; r < 4; ++r) {
            float p = __expf(sv[nt][r] - m_i[r]);
            sv[nt][r] = p;
            rs[r] += p;
        }
#pragma unroll
    for (int r = 0; r < 4; ++r) {
        float t2 = rs[r];
        t2 += __shfl_xor(t2, 1);
        t2 += __shfl_xor(t2, 2);
        t2 += __shfl_xor(t2, 4);
        t2 += __shfl_xor(t2, 8);
        l_i[r] = l_i[r] * alpha[r] + t2;
    }
#pragma unroll
    for (int nt = 0; nt < 4; ++nt)
#pragma unroll
        for (int r = 0; r < 4; ++r) oacc[nt][r] *= alpha[r];

#pragma unroll
    for (int nt = 0; nt < 4; ++nt)
#pragma unroll
        for (int r = 0; r < 4; ++r)
            myp[(quad * 4 + r) * 72 + nt * 16 + l16] = f2bf(sv[nt][r]);

    // V prefetch (kst=1): lands under the kst=0 ds_read + 4 MFMAs.
    BF8 bv1[4];
#pragma unroll
    for (int nt = 0; nt < 4; ++nt)
        bv1[nt].u = *(const uint4*)(vf + ((size_t)(b * 32 + (j0 >> 6)) * 4 + nt) * 1024 +
                                    512 + lane * 8);

    {
        BF8 ap;
        ap.u = *(const uint4*)(myp + l16 * 72 + quad * 8);
#pragma unroll
        for (int nt = 0; nt < 4; ++nt)
            oacc[nt] = __builtin_amdgcn_mfma_f32_16x16x32_bf16(ap.v, bv0[nt].v, oacc[nt], 0, 0, 0);
    }
    {
        BF8 ap;
        ap.u = *(const uint4*)(myp + l16 * 72 + 32 + quad * 8);
#pragma unroll
        for (int nt = 0; nt < 4; ++nt)
            oacc[nt] = __builtin_amdgcn_mfma_f32_16x16x32_bf16(ap.v, bv1[nt].v, oacc[nt], 0, 0, 0);
    }
}

__device__ __forceinline__ void attn_body(int u, int tid, unsigned short* myp,
                                          const unsigned short* __restrict__ qf,
                                          const unsigned short* __restrict__ kf,
                                          const unsigned short* __restrict__ vf,
                                          unsigned short* __restrict__ Opart,
                                          float* __restrict__ mpart,
                                          float* __restrict__ lpart) {
    const int lane = tid & 63;
    const int quad = lane >> 4;
    const int l16 = lane & 15;
    const int b = u / 1088;
    const int rem = u - b * 1088;
    int g = (int)((sqrtf((float)(4 * rem + 1)) - 1.0f) * 0.5f);
    while (4 * (g + 1) * (g + 2) <= rem) ++g;
    while (4 * g * (g + 1) > rem) --g;
    const int off = rem - 4 * g * (g + 1);
    const int nc = g + 1;
    const int qti = off / nc;
    const int kc = off - qti * nc;
    const int qt = g * 8 + qti;
    const int r0 = qt * 16;

    BF8 aq[2];
    {
        const unsigned short* qtile = qf + (size_t)(b * 128 + qt) * 1024;
        aq[0].u = *(const uint4*)(qtile + lane * 8);
        aq[1].u = *(const uint4*)(qtile + 512 + lane * 8);
    }

    floatx4 oacc[4];
#pragma unroll
    for (int nt = 0; nt < 4; ++nt) oacc[nt] = (floatx4)(0.0f);
    float m_i[4], l_i[4];
#pragma unroll
    for (int r = 0; r < 4; ++r) { m_i[r] = -3.0e38f; l_i[r] = 0.0f; }

    // Tile 0 always valid (kc*128 <= r0 by construction); tile 1 iff any of
    // its keys are unmasked for this q-tile.
    const int j0a = kc * 128;
    const bool has2 = (j0a + 64 <= r0 + 15);
    attn_tile(j0a, r0, b, lane, quad, l16, kf, vf, myp, aq, oacc, m_i, l_i);
    if (has2)
        attn_tile(j0a + 64, r0, b, lane, quad, l16, kf, vf, myp, aq, oacc, m_i, l_i);

    // Pack oacc -> LDS (bf16, rows stride 72) -> two contiguous 1KB stores.
#pragma unroll
    for (int nt = 0; nt < 4; ++nt)
#pragma unroll
        for (int r = 0; r < 4; ++r)
            myp[(quad * 4 + r) * 72 + nt * 16 + l16] = f2bf(oacc[nt][r]);
    const size_t ob = (size_t)u * 1024;
    {
        const int row0 = lane >> 3;
        const int c0 = (lane & 7) * 8;
        uint4 a0 = *(const uint4*)(myp + row0 * 72 + c0);
        uint4 a1 = *(const uint4*)(myp + (row0 + 8) * 72 + c0);
        *(uint4*)(Opart + ob + lane * 8) = a0;
        *(uint4*)(Opart + ob + 512 + lane * 8) = a1;
    }
    if (l16 == 0) {
#pragma unroll
        for (int r = 0; r < 4; ++r) {
            mpart[u * 16 + quad * 4 + r] = m_i[r];
            lpart[u * 16 + quad * 4 + r] = l_i[r];
        }
    }
}

// ---------------------------------------------------------------------------
// Phase 3: merge. 256 units x 256 threads; 8 cols/thread, bf16x8 Opart loads.
// ---------------------------------------------------------------------------
__device__ __forceinline__ void merge_body(int u, int tid,
                                           const unsigned short* __restrict__ Opart,
                                           const float* __restrict__ mpart,
                                           const float* __restrict__ lpart,
                                           float* __restrict__ out) {
    const int e = u * 256 + tid;  // 0..65535
    const int cg_ = e & 7;        // col group of 8
    const int row16 = (e >> 3) & 15;
    const int qt = (e >> 7) & 127;
    const int b = e >> 14;
    const int g = qt >> 3;
    const int nc = g + 1;
    const int base_id = b * 1088 + 4 * g * (g + 1) + (qt & 7) * nc;

    float M = -3.0e38f, L = 0.0f;
    float O[8];
#pragma unroll
    for (int j = 0; j < 8; ++j) O[j] = 0.0f;

#pragma unroll 4
    for (int c = 0; c < nc; ++c) {
        const int id = base_id + c;
        const float m_c = mpart[id * 16 + row16];
        const float l_c = lpart[id * 16 + row16];
        BF8 ov;
        ov.u = *(const uint4*)(Opart + (size_t)id * 1024 + row16 * 64 + cg_ * 8);
        const float Mn = fmaxf(M, m_c);
        const float a = __expf(M - Mn);
        const float ec = __expf(m_c - Mn);
        L = L * a + ec * l_c;
#pragma unroll
        for (int j = 0; j < 8; ++j) O[j] = O[j] * a + ec * bf2f(ov.s[j]);
        M = Mn;
    }
    const float inv = 1.0f / L;
    float4 lo, hi;
    lo.x = O[0] * inv; lo.y = O[1] * inv; lo.z = O[2] * inv; lo.w = O[3] * inv;
    hi.x = O[4] * inv; hi.y = O[5] * inv; hi.z = O[6] * inv; hi.w = O[7] * inv;
    float* op = out + ((size_t)((b * 128 + qt) * 16 + row16)) * 64 + cg_ * 8;
    *(float4*)op = lo;
    *(float4*)(op + 4) = hi;
}

// ---------------------------------------------------------------------------
// Fused cooperative kernel.
// ---------------------------------------------------------------------------
extern "C" __global__ __launch_bounds__(256, 4) void fused_head(
    const float* __restrict__ x, const float* __restrict__ Wq,
    const float* __restrict__ Wk, const float* __restrict__ Wv,
    float* __restrict__ out, unsigned short* __restrict__ wtf,
    unsigned short* __restrict__ qf, unsigned short* __restrict__ kf,
    unsigned short* __restrict__ vf, unsigned short* __restrict__ Opart,
    float* __restrict__ mpart, float* __restrict__ lpart) {
    __shared__ __align__(16) unsigned char smem[18432];
    const int tid = threadIdx.x;
    const int bid = blockIdx.x;
    const int nblocks = gridDim.x;
    cg::grid_group grid = cg::this_grid();

    // Phase 0: W transform (48 units).
    for (int u = bid; u < 48; u += nblocks)
        wt_body(u, tid, (unsigned short*)smem, Wq, Wk, Wv, wtf);
    grid.sync();

    // Phase 1: QKV projection (512 units).
    for (int u = bid; u < 512; u += nblocks)
        qkv_body(u, tid, smem, x, wtf, qf, kf, vf);
    grid.sync();

    // Phase 2: flash partials (4352 wave-units).
    {
        const int w = tid >> 6;
        unsigned short* myp = (unsigned short*)smem + w * (16 * 72);
        const int nwaves = nblocks * 4;
        for (int u = bid * 4 + w; u < 4352; u += nwaves)
            attn_body(u, tid, myp, qf, kf, vf, Opart, mpart, lpart);
    }
    grid.sync();

    // Phase 3: merge (256 units).
    for (int u = bid; u < 256; u += nblocks)
        merge_body(u, tid, Opart, mpart, lpart, out);
}

extern "C" void kernel_launch(void* const* d_in, const int* in_sizes, int n_in,
                              void* d_out, int out_size, void* d_ws, size_t ws_size,
                              hipStream_t stream) {
    const float* x = (const float*)d_in[0];
    const float* Wq = (const float*)d_in[1];
    const float* Wk = (const float*)d_in[2];
    const float* Wv = (const float*)d_in[3];
    float* out = (float*)d_out;

    char* ws = (char*)d_ws;
    unsigned short* wtf = (unsigned short*)(ws);
    unsigned short* qf = (unsigned short*)(ws + 393216);
    unsigned short* kf = (unsigned short*)(ws + 1441792);
    unsigned short* vf = (unsigned short*)(ws + 2490368);
    unsigned short* Opart = (unsigned short*)(ws + 3538944);
    float* mpart = (float*)(ws + 12451840ull);
    float* lpart = (float*)(ws + 12730368ull);

    static int grid = 0;
    if (grid == 0) {
        int nb = 0;
        if (hipOccupancyMaxActiveBlocksPerMultiprocessor(&nb, (const void*)fused_head,
                                                         256, 0) != hipSuccess ||
            nb < 1)
            nb = 2;
        long g = (long)nb * 256;
        grid = (int)(g > 1088 ? 1088 : g);
    }

    void* args[12];
    args[0] = (void*)&x;
    args[1] = (void*)&Wq;
    args[2] = (void*)&Wk;
    args[3] = (void*)&Wv;
    args[4] = (void*)&out;
    args[5] = (void*)&wtf;
    args[6] = (void*)&qf;
    args[7] = (void*)&kf;
    args[8] = (void*)&vf;
    args[9] = (void*)&Opart;
    args[10] = (void*)&mpart;
    args[11] = (void*)&lpart;
    hipLaunchCooperativeKernel((const void*)fused_head, dim3(grid), dim3(256), args, 0,
                               stream);
}

// Round 3
// 232.177 us; speedup vs baseline: 1.4573x; 1.4573x over previous
//
#include <hip/hip_runtime.h>
#include <hip/hip_cooperative_groups.h>

namespace cg = cooperative_groups;

// Head: single-head causal attention. B=4, T=2048, D=1024, H=64. fp32 in/out.
// R12: fused cooperative kernel, take 2.
//  - R11 failed because __launch_bounds__(256,4) capped VGPR at 64 -> massive
//    scratch spills (WRITE_SIZE 67.5MB vs ~14MB algorithmic). This round:
//    __launch_bounds__(256,2) (VGPR cap 256, attn needs ~120-160, no spills).
//  - Grid from occupancy query (expect 2-3 blocks/CU -> 512-768 blocks);
//    all phases grid-stride so any grid is correct.
//  - Phase bodies byte-identical to R10's four kernels.
//
// ws layout (bytes):
//   [0,        393216)   wtf   bf16 [12][128][16][8]   (fragment-ordered W)
//   [393216,  1441792)   qf    bf16 [512][8][16][8]    (fragment-ordered Q)
//   [1441792, 2490368)   kf    bf16 [512][8][16][8]
//   [2490368, 3538944)   vf    bf16 [4][32][4][8][16][8]
//   [3538944, 12451840)  Opart bf16 [4352][16][64]     (unit-indexed)
//   [12451840,12730368)  mpart fp32 [4352][16]
//   [12730368,13008896)  lpart fp32 [4352][16]

typedef __attribute__((ext_vector_type(8))) __bf16 bf16x8;
typedef __attribute__((ext_vector_type(4))) float floatx4;

union BF8 {
    bf16x8 v;
    unsigned short s[8];
    uint4 u;
};
union BF4 {
    unsigned short s[4];
    unsigned long long ull;
};

__device__ inline unsigned short f2bf(float f) {
    unsigned int u = __float_as_uint(f);
    unsigned int r = (u + 0x7fffu + ((u >> 16) & 1u)) >> 16;
    return (unsigned short)r;
}
__device__ inline float bf2f(unsigned short s) {
    unsigned int u = ((unsigned int)s) << 16;
    return __uint_as_float(u);
}

// ---------------------------------------------------------------------------
// Phase 0: W -> wtf fragment layout. 48 units.
// ---------------------------------------------------------------------------
__device__ __forceinline__ void wt_body(int u, int tid, unsigned short* lt,
                                        const float* __restrict__ Wq,
                                        const float* __restrict__ Wk,
                                        const float* __restrict__ Wv,
                                        unsigned short* __restrict__ wtf) {
    const int sel = u >> 4;
    const int kb = u & 15;
    const float* W = (sel == 0) ? Wq : (sel == 1) ? Wk : Wv;

    const int h = tid & 63;
    const int kr = tid >> 6;
#pragma unroll
    for (int i = 0; i < 16; ++i) {
        const int kkl = kr + i * 4;
        lt[kkl * 72 + h] = f2bf(W[(size_t)(kb * 64 + kkl) * 64 + h]);
    }
    __syncthreads();

#pragma unroll
    for (int s = 0; s < 2; ++s) {
        const int seg = tid + s * 256;
        const int l16 = seg & 15;
        const int rest = seg >> 4;
        const int ko = rest & 7;
        const int hb = rest >> 3;
        const int hh = hb * 16 + l16;
        BF8 o;
#pragma unroll
        for (int j = 0; j < 8; ++j) o.s[j] = lt[(ko * 8 + j) * 72 + hh];
        const int nblk = sel * 4 + hb;
        const int koct = kb * 8 + ko;
        *(uint4*)(wtf + ((size_t)nblk * 128 + koct) * 128 + l16 * 8) = o.u;
    }
    __syncthreads();
}

// ---------------------------------------------------------------------------
// Phase 1: QKV projection. 512 units (16-row m-tiles).
// ---------------------------------------------------------------------------
__device__ __forceinline__ void qkv_body(int u, int tid, unsigned char* smem,
                                         const float* __restrict__ x,
                                         const unsigned short* __restrict__ wtf,
                                         unsigned short* __restrict__ qf,
                                         unsigned short* __restrict__ kf,
                                         unsigned short* __restrict__ vf) {
    unsigned short* lxbase = (unsigned short*)smem;                 // [2][16*136]
    unsigned short* lt = (unsigned short*)(smem + 8704);            // [16*200]
    unsigned short* vtile = (unsigned short*)(smem + 8704 + 6400);  // [64*24]

    const int w = tid >> 6;  // col-group: 48 cols each
    const int lane = tid & 63;
    const int quad = lane >> 4;
    const int l16 = lane & 15;
    const int m0 = u * 16;
    const int b = m0 >> 11;

    const int srow = tid >> 4;  // 0..15
    const int sc = tid & 15;    // float4 slot (2 per thread: sc, sc+16)

    float4 ld[2];
    const float* xbase = x + (size_t)(m0 + srow) * 1024 + sc * 4;

#define LOAD_CHUNK(c)                               \
    {                                               \
        const float* p_ = xbase + (c) * 128;        \
        ld[0] = *(const float4*)(p_);               \
        ld[1] = *(const float4*)(p_ + 64);          \
    }
#define WRITE_CHUNK(buf)                                              \
    {                                                                 \
        unsigned short* p_ = lxbase + (buf)*2176 + srow * 136 + sc * 4; \
        BF4 b0_, b1_;                                                 \
        b0_.s[0] = f2bf(ld[0].x); b0_.s[1] = f2bf(ld[0].y);           \
        b0_.s[2] = f2bf(ld[0].z); b0_.s[3] = f2bf(ld[0].w);           \
        b1_.s[0] = f2bf(ld[1].x); b1_.s[1] = f2bf(ld[1].y);           \
        b1_.s[2] = f2bf(ld[1].z); b1_.s[3] = f2bf(ld[1].w);           \
        *(unsigned long long*)(p_) = b0_.ull;                         \
        *(unsigned long long*)(p_ + 64) = b1_.ull;                    \
    }

    floatx4 acc[3];
#pragma unroll
    for (int i = 0; i < 3; ++i) acc[i] = (floatx4)(0.0f);

    LOAD_CHUNK(0);
    WRITE_CHUNK(0);
    __syncthreads();

    for (int c = 0; c < 8; ++c) {
        if (c < 7) LOAD_CHUNK(c + 1);
        const unsigned short* lp = lxbase + (c & 1) * 2176 + l16 * 136 + quad * 8;
#pragma unroll
        for (int kst = 0; kst < 4; ++kst) {
            BF8 a;
            a.u = *(const uint4*)(lp + kst * 32);
            const int koct = c * 16 + kst * 4 + quad;
#pragma unroll
            for (int nt = 0; nt < 3; ++nt) {
                const int nb = w * 3 + nt;
                BF8 bfr;
                bfr.u = *(const uint4*)(wtf + ((size_t)nb * 128 + koct) * 128 + l16 * 8);
                acc[nt] = __builtin_amdgcn_mfma_f32_16x16x32_bf16(a.v, bfr.v, acc[nt], 0, 0, 0);
            }
        }
        if (c < 7) WRITE_CHUNK((c + 1) & 1);
        __syncthreads();
    }

    // epilogue: stash C-tiles. cols 0..127 (q,k) -> lt row-major; 128..191 (v)
    // -> vtile (4 consecutive t packed per lane).
#pragma unroll
    for (int nt = 0; nt < 3; ++nt) {
        const int ngl = w * 48 + nt * 16;
        if (ngl < 128) {
#pragma unroll
            for (int r = 0; r < 4; ++r)
                lt[(quad * 4 + r) * 200 + ngl + l16] = f2bf(acc[nt][r]);
        } else {
            BF4 pk;
#pragma unroll
            for (int r = 0; r < 4; ++r) pk.s[r] = f2bf(acc[nt][r]);
            *(unsigned long long*)&vtile[(ngl - 128 + l16) * 24 + quad * 4] = pk.ull;
        }
    }
    __syncthreads();

    // q/k emission: 256 segs of 16B; 16 consecutive tids -> 256B contiguous.
    {
        const int row = tid & 15;
        const int koct = tid >> 4;  // 0..15
        uint4 seg = *(const uint4*)&lt[row * 200 + koct * 8];
        const size_t tile = u;  // = b*128 + qt
        if (koct < 8)
            *(uint4*)(qf + tile * 1024 + koct * 128 + row * 8) = seg;
        else
            *(uint4*)(kf + tile * 1024 + (koct - 8) * 128 + row * 8) = seg;
    }
    // v emission: 128 segs of 16B (8 consecutive t at fixed h).
    if (tid < 128) {
        const int h = tid >> 1;
        const int sg = tid & 1;
        uint4 seg = *(const uint4*)&vtile[h * 24 + sg * 8];
        const int jt = (m0 & 2047) >> 6;
        const int koct = ((m0 & 63) >> 3) + sg;
        *(uint4*)(vf + (((size_t)(b * 32 + jt) * 4 + (h >> 4)) * 8 + koct) * 128 +
                  (h & 15) * 8) = seg;
    }
    __syncthreads();
#undef LOAD_CHUNK
#undef WRITE_CHUNK
}

// ---------------------------------------------------------------------------
// Phase 2: flash pass A. 4352 wave-units. Static two-tile flow + V register
// prefetch + LDS-packed Opart store (R10 code).
// ---------------------------------------------------------------------------
__device__ __forceinline__ void attn_tile(int j0, int r0, int b, int lane, int quad,
                                          int l16,
                                          const unsigned short* __restrict__ kf,
                                          const unsigned short* __restrict__ vf,
                                          unsigned short* myp, const BF8* aq,
                                          floatx4* oacc, float* m_i, float* l_i) {
    floatx4 s[4];
#pragma unroll
    for (int nt = 0; nt < 4; ++nt) s[nt] = (floatx4)(0.0f);
#pragma unroll
    for (int kst = 0; kst < 2; ++kst) {
#pragma unroll
        for (int nt = 0; nt < 4; ++nt) {
            BF8 bk;
            bk.u = *(const uint4*)(kf + (size_t)(b * 128 + (j0 >> 4) + nt) * 1024 +
                                   kst * 512 + lane * 8);
            s[nt] = __builtin_amdgcn_mfma_f32_16x16x32_bf16(aq[kst].v, bk.v, s[nt], 0, 0, 0);
        }
    }

    // V prefetch (kst=0): independent of softmax -> lands under softmax VALU.
    BF8 bv0[4];
#pragma unroll
    for (int nt = 0; nt < 4; ++nt)
        bv0[nt].u = *(const uint4*)(vf + ((size_t)(b * 32 + (j0 >> 6)) * 4 + nt) * 1024 +
                                    lane * 8);

    float sv[4][4];
    const bool masked = (j0 + 63 > r0);
#pragma unroll
    for (int nt = 0; nt < 4; ++nt)
#pragma unroll
        for (int r = 0; r < 4; ++r) {
            float val = s[nt][r] * 0.125f;
            if (masked) {
                int key = j0 + nt * 16 + l16;
                int qr = r0 + quad * 4 + r;
                if (key > qr) val = -3.0e38f;
            }
            sv[nt][r] = val;
        }

    float alpha[4];
#pragma unroll
    for (int r = 0; r < 4; ++r) {
        float mx = fmaxf(fmaxf(sv[0][r], sv[1][r]), fmaxf(sv[2][r], sv[3][r]));
        mx = fmaxf(mx, __shfl_xor(mx, 1));
        mx = fmaxf(mx, __shfl_xor(mx, 2));
        mx = fmaxf(mx, __shfl_xor(mx, 4));
        mx = fmaxf(mx, __shfl_xor(mx, 8));
        float mn = fmaxf(m_i[r], mx);
        alpha[r] = __expf(m_i[r] - mn);
        m_i[r] = mn;
    }
    float rs[4] = {0.f, 0.f, 0.f, 0.f};
#pragma unroll
    for (int nt = 0; nt < 4; ++nt)
#pragma unroll
        for (int r = 0; r < 4; ++r) {
            float p = __expf(sv[nt][r] - m_i[r]);
            sv[nt][r] = p;
            rs[r] += p;
        }
#pragma unroll
    for (int r = 0; r < 4; ++r) {
        float t2 = rs[r];
        t2 += __shfl_xor(t2, 1);
        t2 += __shfl_xor(t2, 2);
        t2 += __shfl_xor(t2, 4);
        t2 += __shfl_xor(t2, 8);
        l_i[r] = l_i[r] * alpha[r] + t2;
    }
#pragma unroll
    for (int nt = 0; nt < 4; ++nt)
#pragma unroll
        for (int r = 0; r < 4; ++r) oacc[nt][r] *= alpha[r];

#pragma unroll
    for (int nt = 0; nt < 4; ++nt)
#pragma unroll
        for (int r = 0; r < 4; ++r)
            myp[(quad * 4 + r) * 72 + nt * 16 + l16] = f2bf(sv[nt][r]);

    // V prefetch (kst=1): lands under the kst=0 ds_read + 4 MFMAs.
    BF8 bv1[4];
#pragma unroll
    for (int nt = 0; nt < 4; ++nt)
        bv1[nt].u = *(const uint4*)(vf + ((size_t)(b * 32 + (j0 >> 6)) * 4 + nt) * 1024 +
                                    512 + lane * 8);

    {
        BF8 ap;
        ap.u = *(const uint4*)(myp + l16 * 72 + quad * 8);
#pragma unroll
        for (int nt = 0; nt < 4; ++nt)
            oacc[nt] = __builtin_amdgcn_mfma_f32_16x16x32_bf16(ap.v, bv0[nt].v, oacc[nt], 0, 0, 0);
    }
    {
        BF8 ap;
        ap.u = *(const uint4*)(myp + l16 * 72 + 32 + quad * 8);
#pragma unroll
        for (int nt = 0; nt < 4; ++nt)
            oacc[nt] = __builtin_amdgcn_mfma_f32_16x16x32_bf16(ap.v, bv1[nt].v, oacc[nt], 0, 0, 0);
    }
}

__device__ __forceinline__ void attn_body(int u, int tid, unsigned short* myp,
                                          const unsigned short* __restrict__ qf,
                                          const unsigned short* __restrict__ kf,
                                          const unsigned short* __restrict__ vf,
                                          unsigned short* __restrict__ Opart,
                                          float* __restrict__ mpart,
                                          float* __restrict__ lpart) {
    const int lane = tid & 63;
    const int quad = lane >> 4;
    const int l16 = lane & 15;
    const int b = u / 1088;
    const int rem = u - b * 1088;
    int g = (int)((sqrtf((float)(4 * rem + 1)) - 1.0f) * 0.5f);
    while (4 * (g + 1) * (g + 2) <= rem) ++g;
    while (4 * g * (g + 1) > rem) --g;
    const int off = rem - 4 * g * (g + 1);
    const int nc = g + 1;
    const int qti = off / nc;
    const int kc = off - qti * nc;
    const int qt = g * 8 + qti;
    const int r0 = qt * 16;

    BF8 aq[2];
    {
        const unsigned short* qtile = qf + (size_t)(b * 128 + qt) * 1024;
        aq[0].u = *(const uint4*)(qtile + lane * 8);
        aq[1].u = *(const uint4*)(qtile + 512 + lane * 8);
    }

    floatx4 oacc[4];
#pragma unroll
    for (int nt = 0; nt < 4; ++nt) oacc[nt] = (floatx4)(0.0f);
    float m_i[4], l_i[4];
#pragma unroll
    for (int r = 0; r < 4; ++r) { m_i[r] = -3.0e38f; l_i[r] = 0.0f; }

    // Tile 0 always valid (kc*128 <= r0 by construction); tile 1 iff any of
    // its keys are unmasked for this q-tile.
    const int j0a = kc * 128;
    const bool has2 = (j0a + 64 <= r0 + 15);
    attn_tile(j0a, r0, b, lane, quad, l16, kf, vf, myp, aq, oacc, m_i, l_i);
    if (has2)
        attn_tile(j0a + 64, r0, b, lane, quad, l16, kf, vf, myp, aq, oacc, m_i, l_i);

    // Pack oacc -> LDS (bf16, rows stride 72) -> two contiguous 1KB stores.
#pragma unroll
    for (int nt = 0; nt < 4; ++nt)
#pragma unroll
        for (int r = 0; r < 4; ++r)
            myp[(quad * 4 + r) * 72 + nt * 16 + l16] = f2bf(oacc[nt][r]);
    const size_t ob = (size_t)u * 1024;
    {
        const int row0 = lane >> 3;
        const int c0 = (lane & 7) * 8;
        uint4 a0 = *(const uint4*)(myp + row0 * 72 + c0);
        uint4 a1 = *(const uint4*)(myp + (row0 + 8) * 72 + c0);
        *(uint4*)(Opart + ob + lane * 8) = a0;
        *(uint4*)(Opart + ob + 512 + lane * 8) = a1;
    }
    if (l16 == 0) {
#pragma unroll
        for (int r = 0; r < 4; ++r) {
            mpart[u * 16 + quad * 4 + r] = m_i[r];
            lpart[u * 16 + quad * 4 + r] = l_i[r];
        }
    }
}

// ---------------------------------------------------------------------------
// Phase 3: merge. 256 units x 256 threads; 8 cols/thread, bf16x8 Opart loads.
// ---------------------------------------------------------------------------
__device__ __forceinline__ void merge_body(int u, int tid,
                                           const unsigned short* __restrict__ Opart,
                                           const float* __restrict__ mpart,
                                           const float* __restrict__ lpart,
                                           float* __restrict__ out) {
    const int e = u * 256 + tid;  // 0..65535
    const int cg_ = e & 7;        // col group of 8
    const int row16 = (e >> 3) & 15;
    const int qt = (e >> 7) & 127;
    const int b = e >> 14;
    const int g = qt >> 3;
    const int nc = g + 1;
    const int base_id = b * 1088 + 4 * g * (g + 1) + (qt & 7) * nc;

    float M = -3.0e38f, L = 0.0f;
    float O[8];
#pragma unroll
    for (int j = 0; j < 8; ++j) O[j] = 0.0f;

#pragma unroll 4
    for (int c = 0; c < nc; ++c) {
        const int id = base_id + c;
        const float m_c = mpart[id * 16 + row16];
        const float l_c = lpart[id * 16 + row16];
        BF8 ov;
        ov.u = *(const uint4*)(Opart + (size_t)id * 1024 + row16 * 64 + cg_ * 8);
        const float Mn = fmaxf(M, m_c);
        const float a = __expf(M - Mn);
        const float ec = __expf(m_c - Mn);
        L = L * a + ec * l_c;
#pragma unroll
        for (int j = 0; j < 8; ++j) O[j] = O[j] * a + ec * bf2f(ov.s[j]);
        M = Mn;
    }
    const float inv = 1.0f / L;
    float4 lo, hi;
    lo.x = O[0] * inv; lo.y = O[1] * inv; lo.z = O[2] * inv; lo.w = O[3] * inv;
    hi.x = O[4] * inv; hi.y = O[5] * inv; hi.z = O[6] * inv; hi.w = O[7] * inv;
    float* op = out + ((size_t)((b * 128 + qt) * 16 + row16)) * 64 + cg_ * 8;
    *(float4*)op = lo;
    *(float4*)(op + 4) = hi;
}

// ---------------------------------------------------------------------------
// Fused cooperative kernel. __launch_bounds__(256,2): VGPR cap 256 -> no
// spills (R11's (256,4) capped at 64 VGPR -> scratch thrash, 4x slowdown).
// ---------------------------------------------------------------------------
extern "C" __global__ __launch_bounds__(256, 2) void fused_head(
    const float* __restrict__ x, const float* __restrict__ Wq,
    const float* __restrict__ Wk, const float* __restrict__ Wv,
    float* __restrict__ out, unsigned short* __restrict__ wtf,
    unsigned short* __restrict__ qf, unsigned short* __restrict__ kf,
    unsigned short* __restrict__ vf, unsigned short* __restrict__ Opart,
    float* __restrict__ mpart, float* __restrict__ lpart) {
    __shared__ __align__(16) unsigned char smem[18432];
    const int tid = threadIdx.x;
    const int bid = blockIdx.x;
    const int nblocks = gridDim.x;
    cg::grid_group grid = cg::this_grid();

    // Phase 0: W transform (48 units).
    for (int u = bid; u < 48; u += nblocks)
        wt_body(u, tid, (unsigned short*)smem, Wq, Wk, Wv, wtf);
    grid.sync();

    // Phase 1: QKV projection (512 units).
    for (int u = bid; u < 512; u += nblocks)
        qkv_body(u, tid, smem, x, wtf, qf, kf, vf);
    grid.sync();

    // Phase 2: flash partials (4352 wave-units).
    {
        const int w = tid >> 6;
        unsigned short* myp = (unsigned short*)smem + w * (16 * 72);
        const int nwaves = nblocks * 4;
        for (int u = bid * 4 + w; u < 4352; u += nwaves)
            attn_body(u, tid, myp, qf, kf, vf, Opart, mpart, lpart);
    }
    grid.sync();

    // Phase 3: merge (256 units).
    for (int u = bid; u < 256; u += nblocks)
        merge_body(u, tid, Opart, mpart, lpart, out);
}

extern "C" void kernel_launch(void* const* d_in, const int* in_sizes, int n_in,
                              void* d_out, int out_size, void* d_ws, size_t ws_size,
                              hipStream_t stream) {
    const float* x = (const float*)d_in[0];
    const float* Wq = (const float*)d_in[1];
    const float* Wk = (const float*)d_in[2];
    const float* Wv = (const float*)d_in[3];
    float* out = (float*)d_out;

    char* ws = (char*)d_ws;
    unsigned short* wtf = (unsigned short*)(ws);
    unsigned short* qf = (unsigned short*)(ws + 393216);
    unsigned short* kf = (unsigned short*)(ws + 1441792);
    unsigned short* vf = (unsigned short*)(ws + 2490368);
    unsigned short* Opart = (unsigned short*)(ws + 3538944);
    float* mpart = (float*)(ws + 12451840ull);
    float* lpart = (float*)(ws + 12730368ull);

    static int grid = 0;
    if (grid == 0) {
        int nb = 0;
        if (hipOccupancyMaxActiveBlocksPerMultiprocessor(&nb, (const void*)fused_head,
                                                         256, 0) != hipSuccess ||
            nb < 1)
            nb = 2;
        long g = (long)nb * 256;
        grid = (int)(g > 1088 ? 1088 : g);
    }

    void* args[12];
    args[0] = (void*)&x;
    args[1] = (void*)&Wq;
    args[2] = (void*)&Wk;
    args[3] = (void*)&Wv;
    args[4] = (void*)&out;
    args[5] = (void*)&wtf;
    args[6] = (void*)&qf;
    args[7] = (void*)&kf;
    args[8] = (void*)&vf;
    args[9] = (void*)&Opart;
    args[10] = (void*)&mpart;
    args[11] = (void*)&lpart;
    hipLaunchCooperativeKernel((const void*)fused_head, dim3(grid), dim3(256), args, 0,
                               stream);
}

// Round 4
// 98.313 us; speedup vs baseline: 3.4415x; 2.3616x over previous
//
#include <hip/hip_runtime.h>

// Head: single-head causal attention. B=4, T=2048, D=1024, H=64. fp32 in/out.
// R13: back to multi-dispatch (cooperative fusion dead per R11/R12); fuse
// attn+merge BLOCK-LOCALLY instead:
//  - attn_fused: 512 blocks (one per (b,qt) row) x 8 waves. Wave w does
//    chunks kc=w,w+8 with ONLINE softmax across its chunks (fp32 running
//    m/l/oacc). Partials -> LDS (fp32), __syncthreads, 8-way merge, write
//    out directly. Eliminates merge dispatch + all Opart/mpart/lpart
//    global traffic + bf16 partial quantization + sqrt index decode.
//  - Load balance: 4352 chunk-units / 4096 waves, max 2 per wave. Largest
//    rows scheduled first (qt = 127 - bid>>2).
//  - wt/qkv byte-identical to R10. 3 dispatches total.
//
// ws layout (bytes):
//   [0,        393216)   wtf   bf16 [12][128][16][8]   (fragment-ordered W)
//   [393216,  1441792)   qf    bf16 [512][8][16][8]    (fragment-ordered Q)
//   [1441792, 2490368)   kf    bf16 [512][8][16][8]
//   [2490368, 3538944)   vf    bf16 [4][32][4][8][16][8]

typedef __attribute__((ext_vector_type(8))) __bf16 bf16x8;
typedef __attribute__((ext_vector_type(4))) float floatx4;

union BF8 {
    bf16x8 v;
    unsigned short s[8];
    uint4 u;
};
union BF4 {
    unsigned short s[4];
    unsigned long long ull;
};

__device__ inline unsigned short f2bf(float f) {
    unsigned int u = __float_as_uint(f);
    unsigned int r = (u + 0x7fffu + ((u >> 16) & 1u)) >> 16;
    return (unsigned short)r;
}

// ---------------------------------------------------------------------------
// Kernel 0: W -> wtf fragment layout (R10 code). Grid 48 = 3 x 16.
// ---------------------------------------------------------------------------
__global__ __launch_bounds__(256) void wt_kernel(const float* __restrict__ Wq,
                                                 const float* __restrict__ Wk,
                                                 const float* __restrict__ Wv,
                                                 unsigned short* __restrict__ wtf) {
    __shared__ __align__(16) unsigned short lt[64 * 72];
    const int tid = threadIdx.x;
    const int sel = blockIdx.x >> 4;
    const int kb = blockIdx.x & 15;
    const float* W = (sel == 0) ? Wq : (sel == 1) ? Wk : Wv;

    const int h = tid & 63;
    const int kr = tid >> 6;
#pragma unroll
    for (int i = 0; i < 16; ++i) {
        const int kkl = kr + i * 4;
        lt[kkl * 72 + h] = f2bf(W[(size_t)(kb * 64 + kkl) * 64 + h]);
    }
    __syncthreads();

#pragma unroll
    for (int s = 0; s < 2; ++s) {
        const int seg = tid + s * 256;
        const int l16 = seg & 15;
        const int rest = seg >> 4;
        const int ko = rest & 7;
        const int hb = rest >> 3;
        const int hh = hb * 16 + l16;
        BF8 o;
#pragma unroll
        for (int j = 0; j < 8; ++j) o.s[j] = lt[(ko * 8 + j) * 72 + hh];
        const int nblk = sel * 4 + hb;
        const int koct = kb * 8 + ko;
        *(uint4*)(wtf + ((size_t)nblk * 128 + koct) * 128 + l16 * 8) = o.u;
    }
}

// ---------------------------------------------------------------------------
// Kernel 1: QKV projection (R10 code). Grid 512 m-tiles(16 rows) x 256 thr.
// ---------------------------------------------------------------------------
__global__ __launch_bounds__(256) void qkv_kernel(const float* __restrict__ x,
                                                  const unsigned short* __restrict__ wtf,
                                                  unsigned short* __restrict__ qf,
                                                  unsigned short* __restrict__ kf,
                                                  unsigned short* __restrict__ vf) {
    __shared__ __align__(16) unsigned short lx[2][16 * 136];
    __shared__ __align__(16) unsigned short lt[16 * 200];
    __shared__ __align__(16) unsigned short vtile[64 * 24];
    const int tid = threadIdx.x;
    const int w = tid >> 6;  // col-group: 48 cols each
    const int lane = tid & 63;
    const int quad = lane >> 4;
    const int l16 = lane & 15;
    const int m0 = blockIdx.x * 16;
    const int b = m0 >> 11;

    const int srow = tid >> 4;  // 0..15
    const int sc = tid & 15;    // float4 slot (2 per thread: sc, sc+16)

    float4 ld[2];
    const float* xbase = x + (size_t)(m0 + srow) * 1024 + sc * 4;

#define LOAD_CHUNK(c)                               \
    {                                               \
        const float* p_ = xbase + (c) * 128;        \
        ld[0] = *(const float4*)(p_);               \
        ld[1] = *(const float4*)(p_ + 64);          \
    }
#define WRITE_CHUNK(buf)                                           \
    {                                                              \
        unsigned short* p_ = &lx[buf][0] + srow * 136 + sc * 4;    \
        BF4 b0_, b1_;                                              \
        b0_.s[0] = f2bf(ld[0].x); b0_.s[1] = f2bf(ld[0].y);        \
        b0_.s[2] = f2bf(ld[0].z); b0_.s[3] = f2bf(ld[0].w);        \
        b1_.s[0] = f2bf(ld[1].x); b1_.s[1] = f2bf(ld[1].y);        \
        b1_.s[2] = f2bf(ld[1].z); b1_.s[3] = f2bf(ld[1].w);        \
        *(unsigned long long*)(p_) = b0_.ull;                      \
        *(unsigned long long*)(p_ + 64) = b1_.ull;                 \
    }

    floatx4 acc[3];
#pragma unroll
    for (int i = 0; i < 3; ++i) acc[i] = (floatx4)(0.0f);

    LOAD_CHUNK(0);
    WRITE_CHUNK(0);
    __syncthreads();

    for (int c = 0; c < 8; ++c) {
        if (c < 7) LOAD_CHUNK(c + 1);
        const unsigned short* lp = &lx[c & 1][0] + l16 * 136 + quad * 8;
#pragma unroll
        for (int kst = 0; kst < 4; ++kst) {
            BF8 a;
            a.u = *(const uint4*)(lp + kst * 32);
            const int koct = c * 16 + kst * 4 + quad;
#pragma unroll
            for (int nt = 0; nt < 3; ++nt) {
                const int nb = w * 3 + nt;
                BF8 bfr;
                bfr.u = *(const uint4*)(wtf + ((size_t)nb * 128 + koct) * 128 + l16 * 8);
                acc[nt] = __builtin_amdgcn_mfma_f32_16x16x32_bf16(a.v, bfr.v, acc[nt], 0, 0, 0);
            }
        }
        if (c < 7) WRITE_CHUNK((c + 1) & 1);
        __syncthreads();
    }

    // epilogue: stash C-tiles. cols 0..127 (q,k) -> lt row-major; 128..191 (v)
    // -> vtile (4 consecutive t packed per lane).
#pragma unroll
    for (int nt = 0; nt < 3; ++nt) {
        const int ngl = w * 48 + nt * 16;
        if (ngl < 128) {
#pragma unroll
            for (int r = 0; r < 4; ++r)
                lt[(quad * 4 + r) * 200 + ngl + l16] = f2bf(acc[nt][r]);
        } else {
            BF4 pk;
#pragma unroll
            for (int r = 0; r < 4; ++r) pk.s[r] = f2bf(acc[nt][r]);
            *(unsigned long long*)&vtile[(ngl - 128 + l16) * 24 + quad * 4] = pk.ull;
        }
    }
    __syncthreads();

    // q/k emission: 256 segs of 16B; 16 consecutive tids -> 256B contiguous.
    {
        const int row = tid & 15;
        const int koct = tid >> 4;  // 0..15
        uint4 seg = *(const uint4*)&lt[row * 200 + koct * 8];
        const size_t tile = blockIdx.x;  // = b*128 + qt
        if (koct < 8)
            *(uint4*)(qf + tile * 1024 + koct * 128 + row * 8) = seg;
        else
            *(uint4*)(kf + tile * 1024 + (koct - 8) * 128 + row * 8) = seg;
    }
    // v emission: 128 segs of 16B (8 consecutive t at fixed h).
    if (tid < 128) {
        const int h = tid >> 1;
        const int sg = tid & 1;
        uint4 seg = *(const uint4*)&vtile[h * 24 + sg * 8];
        const int jt = (m0 & 2047) >> 6;
        const int koct = ((m0 & 63) >> 3) + sg;
        *(uint4*)(vf + (((size_t)(b * 32 + jt) * 4 + (h >> 4)) * 8 + koct) * 128 +
                  (h & 15) * 8) = seg;
    }
#undef LOAD_CHUNK
#undef WRITE_CHUNK
}

// ---------------------------------------------------------------------------
// Kernel 2: fused flash + merge. One block per (b,qt) row; 8 waves; wave w
// owns chunks kc=w,w+8 (online softmax across chunks); fp32 partials in LDS;
// block-local 8-way merge; direct out write.
// ---------------------------------------------------------------------------
__device__ __forceinline__ void attn_tile(int j0, int r0, int b, int lane, int quad,
                                          int l16,
                                          const unsigned short* __restrict__ kf,
                                          const unsigned short* __restrict__ vf,
                                          unsigned short* myp, const BF8* aq,
                                          floatx4* oacc, float* m_i, float* l_i) {
    floatx4 s[4];
#pragma unroll
    for (int nt = 0; nt < 4; ++nt) s[nt] = (floatx4)(0.0f);
#pragma unroll
    for (int kst = 0; kst < 2; ++kst) {
#pragma unroll
        for (int nt = 0; nt < 4; ++nt) {
            BF8 bk;
            bk.u = *(const uint4*)(kf + (size_t)(b * 128 + (j0 >> 4) + nt) * 1024 +
                                   kst * 512 + lane * 8);
            s[nt] = __builtin_amdgcn_mfma_f32_16x16x32_bf16(aq[kst].v, bk.v, s[nt], 0, 0, 0);
        }
    }

    // V prefetch (kst=0): independent of softmax -> lands under softmax VALU.
    BF8 bv0[4];
#pragma unroll
    for (int nt = 0; nt < 4; ++nt)
        bv0[nt].u = *(const uint4*)(vf + ((size_t)(b * 32 + (j0 >> 6)) * 4 + nt) * 1024 +
                                    lane * 8);

    float sv[4][4];
    const bool masked = (j0 + 63 > r0);
#pragma unroll
    for (int nt = 0; nt < 4; ++nt)
#pragma unroll
        for (int r = 0; r < 4; ++r) {
            float val = s[nt][r] * 0.125f;
            if (masked) {
                int key = j0 + nt * 16 + l16;
                int qr = r0 + quad * 4 + r;
                if (key > qr) val = -3.0e38f;
            }
            sv[nt][r] = val;
        }

    float alpha[4];
#pragma unroll
    for (int r = 0; r < 4; ++r) {
        float mx = fmaxf(fmaxf(sv[0][r], sv[1][r]), fmaxf(sv[2][r], sv[3][r]));
        mx = fmaxf(mx, __shfl_xor(mx, 1));
        mx = fmaxf(mx, __shfl_xor(mx, 2));
        mx = fmaxf(mx, __shfl_xor(mx, 4));
        mx = fmaxf(mx, __shfl_xor(mx, 8));
        float mn = fmaxf(m_i[r], mx);
        alpha[r] = __expf(m_i[r] - mn);
        m_i[r] = mn;
    }
    float rs[4] = {0.f, 0.f, 0.f, 0.f};
#pragma unroll
    for (int nt = 0; nt < 4; ++nt)
#pragma unroll
        for (int r = 0; r < 4; ++r) {
            float p = __expf(sv[nt][r] - m_i[r]);
            sv[nt][r] = p;
            rs[r] += p;
        }
#pragma unroll
    for (int r = 0; r < 4; ++r) {
        float t2 = rs[r];
        t2 += __shfl_xor(t2, 1);
        t2 += __shfl_xor(t2, 2);
        t2 += __shfl_xor(t2, 4);
        t2 += __shfl_xor(t2, 8);
        l_i[r] = l_i[r] * alpha[r] + t2;
    }
#pragma unroll
    for (int nt = 0; nt < 4; ++nt)
#pragma unroll
        for (int r = 0; r < 4; ++r) oacc[nt][r] *= alpha[r];

#pragma unroll
    for (int nt = 0; nt < 4; ++nt)
#pragma unroll
        for (int r = 0; r < 4; ++r)
            myp[(quad * 4 + r) * 72 + nt * 16 + l16] = f2bf(sv[nt][r]);

    // V prefetch (kst=1): lands under the kst=0 ds_read + 4 MFMAs.
    BF8 bv1[4];
#pragma unroll
    for (int nt = 0; nt < 4; ++nt)
        bv1[nt].u = *(const uint4*)(vf + ((size_t)(b * 32 + (j0 >> 6)) * 4 + nt) * 1024 +
                                    512 + lane * 8);

    {
        BF8 ap;
        ap.u = *(const uint4*)(myp + l16 * 72 + quad * 8);
#pragma unroll
        for (int nt = 0; nt < 4; ++nt)
            oacc[nt] = __builtin_amdgcn_mfma_f32_16x16x32_bf16(ap.v, bv0[nt].v, oacc[nt], 0, 0, 0);
    }
    {
        BF8 ap;
        ap.u = *(const uint4*)(myp + l16 * 72 + 32 + quad * 8);
#pragma unroll
        for (int nt = 0; nt < 4; ++nt)
            oacc[nt] = __builtin_amdgcn_mfma_f32_16x16x32_bf16(ap.v, bv1[nt].v, oacc[nt], 0, 0, 0);
    }
}

__global__ __launch_bounds__(512) void attn_fused(const unsigned short* __restrict__ qf,
                                                  const unsigned short* __restrict__ kf,
                                                  const unsigned short* __restrict__ vf,
                                                  float* __restrict__ out) {
    // LDS: 8 x P-scratch (bf16 16x72) + 8 x fp32 partial (16x68) + m/l.
    __shared__ __align__(16) unsigned short myp_all[8 * 16 * 72];  // 18432 B
    __shared__ __align__(16) float opart[8][16 * 68];              // 34816 B
    __shared__ float mlds[8 * 16];
    __shared__ float llds[8 * 16];

    const int tid = threadIdx.x;
    const int w = tid >> 6;  // 0..7
    const int lane = tid & 63;
    const int quad = lane >> 4;
    const int l16 = lane & 15;

    // Largest rows first: bid 0 -> qt=127.
    const int qt = 127 - (blockIdx.x >> 2);
    const int b = blockIdx.x & 3;
    const int r0 = qt * 16;
    const int nc = (qt >> 3) + 1;  // #chunks of 128 keys

    BF8 aq[2];
    {
        const unsigned short* qtile = qf + (size_t)(b * 128 + qt) * 1024;
        aq[0].u = *(const uint4*)(qtile + lane * 8);
        aq[1].u = *(const uint4*)(qtile + 512 + lane * 8);
    }

    floatx4 oacc[4];
#pragma unroll
    for (int nt = 0; nt < 4; ++nt) oacc[nt] = (floatx4)(0.0f);
    float m_i[4], l_i[4];
#pragma unroll
    for (int r = 0; r < 4; ++r) { m_i[r] = -3.0e38f; l_i[r] = 0.0f; }

    unsigned short* myp = myp_all + w * (16 * 72);

    // Online softmax across this wave's chunks (kc = w, w+8).
    for (int kc = w; kc < nc; kc += 8) {
        const int j0 = kc << 7;
        attn_tile(j0, r0, b, lane, quad, l16, kf, vf, myp, aq, oacc, m_i, l_i);
        if (j0 + 64 <= r0 + 15)
            attn_tile(j0 + 64, r0, b, lane, quad, l16, kf, vf, myp, aq, oacc, m_i, l_i);
    }

    // Publish wave partial (fp32) to LDS. Idle waves publish the neutral
    // element (oacc=0, m=-3e38, l=0).
#pragma unroll
    for (int nt = 0; nt < 4; ++nt)
#pragma unroll
        for (int r = 0; r < 4; ++r)
            opart[w][(quad * 4 + r) * 68 + nt * 16 + l16] = oacc[nt][r];
    if (l16 == 0) {
#pragma unroll
        for (int r = 0; r < 4; ++r) {
            mlds[w * 16 + quad * 4 + r] = m_i[r];
            llds[w * 16 + quad * 4 + r] = l_i[r];
        }
    }
    __syncthreads();

    // 8-way merge: 512 threads, 2 cols each. Wave 0 always has work -> L>0.
    {
        const int row16 = tid >> 5;  // 0..15
        const int c2 = tid & 31;     // col pair
        float M = -3.0e38f, L = 0.0f, O0 = 0.0f, O1 = 0.0f;
#pragma unroll
        for (int w2 = 0; w2 < 8; ++w2) {
            const float m_c = mlds[w2 * 16 + row16];
            const float l_c = llds[w2 * 16 + row16];
            const float2 oc = *(const float2*)&opart[w2][row16 * 68 + c2 * 2];
            const float Mn = fmaxf(M, m_c);
            const float a = __expf(M - Mn);
            const float ec = __expf(m_c - Mn);
            L = L * a + ec * l_c;
            O0 = O0 * a + ec * oc.x;
            O1 = O1 * a + ec * oc.y;
            M = Mn;
        }
        const float inv = 1.0f / L;
        float2 o;
        o.x = O0 * inv;
        o.y = O1 * inv;
        *(float2*)(out + ((size_t)(b * 2048 + qt * 16 + row16)) * 64 + c2 * 2) = o;
    }
}

extern "C" void kernel_launch(void* const* d_in, const int* in_sizes, int n_in,
                              void* d_out, int out_size, void* d_ws, size_t ws_size,
                              hipStream_t stream) {
    const float* x = (const float*)d_in[0];
    const float* Wq = (const float*)d_in[1];
    const float* Wk = (const float*)d_in[2];
    const float* Wv = (const float*)d_in[3];
    float* out = (float*)d_out;

    char* ws = (char*)d_ws;
    unsigned short* wtf = (unsigned short*)(ws);
    unsigned short* qf = (unsigned short*)(ws + 393216);
    unsigned short* kf = (unsigned short*)(ws + 1441792);
    unsigned short* vf = (unsigned short*)(ws + 2490368);

    hipLaunchKernelGGL(wt_kernel, dim3(48), dim3(256), 0, stream, Wq, Wk, Wv, wtf);
    hipLaunchKernelGGL(qkv_kernel, dim3(512), dim3(256), 0, stream, x, wtf, qf, kf, vf);
    hipLaunchKernelGGL(attn_fused, dim3(512), dim3(512), 0, stream, qf, kf, vf, out);
}